// Round 10
// baseline (338.547 us; speedup 1.0000x reference)
//
#include <hip/hip_runtime.h>
#include <hip/hip_fp16.h>

#define IN_F 128
#define OUT_F 64
#define NB    256     // node-range buckets, 512 nodes each
#define BSH   9
#define CAP   3840    // per-bucket capacity (lambda=2344, +31 sigma, proven R4-R7)
#define CHUNK 2048    // edges per bin block
#define KPF  136      // Fh k-pitch (bf16 elems)
#define KPW  144      // Wt k-pitch (bf16 elems)

using short8  = __attribute__((ext_vector_type(8))) short;
using float4v = __attribute__((ext_vector_type(4))) float;

static __device__ inline unsigned short f2bf(float x) {
    union { float f; unsigned u; } v; v.f = x;
    unsigned r = (v.u + 0x7fffu + ((v.u >> 16) & 1u)) >> 16;  // RN-even
    return (unsigned short)r;
}

// ---- fused pass 1: edge binning INTERLEAVED with GEMM (R8's proven kernel) --
__global__ __launch_bounds__(256) void bin_gemm_kernel(
    const int* __restrict__ src, const int* __restrict__ dst,
    int* __restrict__ gcur_d, int* __restrict__ gcur_s,
    unsigned* __restrict__ bkt_d, unsigned short* __restrict__ bkt_s,
    int E, int nbin,
    const float* __restrict__ feat, const float* __restrict__ W,
    __half* __restrict__ h, int n)
{
    __shared__ union {
        struct { int hd[NB]; int hs[NB]; int based[NB]; int bases[NB]; } bin;
        struct { unsigned short Fh[128 * KPF]; unsigned short Wt[64 * KPW]; } gm;
    } smem;

    const int tid = threadIdx.x;
    const int b   = blockIdx.x;
    const int G   = gridDim.x;
    const int f   = (int)(((long)b       * nbin) / G);   // bin blocks before b
    const int c   = (int)(((long)(b + 1) * nbin) / G);
    const bool is_bin = (c > f);

    if (is_bin) {
        // ---------------- bin path (proven structure; bin block index = f) ---
        const int e0 = f * CHUNK;

        smem.bin.hd[tid] = 0; smem.bin.hs[tid] = 0;
        __syncthreads();

        int sv[8], dv[8];
        #pragma unroll
        for (int j = 0; j < 8; ++j) {
            int i = e0 + j * 256 + tid;          // coalesced
            if (i < E) { sv[j] = src[i]; dv[j] = dst[i]; }
            else       { sv[j] = -1;     dv[j] = -1; }
        }
        #pragma unroll
        for (int j = 0; j < 8; ++j) {
            if (dv[j] >= 0) {
                atomicAdd(&smem.bin.hd[dv[j] >> BSH], 1);
                atomicAdd(&smem.bin.hs[sv[j] >> BSH], 1);
            }
        }
        __syncthreads();

        int cd = smem.bin.hd[tid], cs = smem.bin.hs[tid];
        smem.bin.based[tid] = cd ? atomicAdd(&gcur_d[tid], cd) : 0;
        smem.bin.bases[tid] = cs ? atomicAdd(&gcur_s[tid], cs) : 0;
        smem.bin.hd[tid] = 0; smem.bin.hs[tid] = 0;   // reuse as local cursors
        __syncthreads();

        #pragma unroll
        for (int j = 0; j < 8; ++j) {
            if (dv[j] >= 0) {
                int bd = dv[j] >> BSH;
                int pd = atomicAdd(&smem.bin.hd[bd], 1) + smem.bin.based[bd];
                if (pd < CAP)
                    bkt_d[(size_t)bd * CAP + pd] =
                        (unsigned)sv[j] | ((unsigned)(dv[j] & 511) << 17);  // src < 2^17
                int bs = sv[j] >> BSH;
                int ps = atomicAdd(&smem.bin.hs[bs], 1) + smem.bin.bases[bs];
                if (ps < CAP) bkt_s[(size_t)bs * CAP + ps] = (unsigned short)(sv[j] & 511);
            }
        }
        return;
    }

    // ---------------- gemm path: h = feat @ W (raw fp16; ns applied in gather)
    unsigned short* Fh = smem.gm.Fh;
    unsigned short* Wt = smem.gm.Wt;
    const int row0 = (b - f) * 128;           // gemm block index = b - f

    {
        const float4* W4 = (const float4*)W;
        #pragma unroll
        for (int it = 0; it < 8; ++it) {
            int i4 = it * 256 + tid;
            int k  = i4 >> 4;
            int c4 = (i4 & 15) * 4;
            float4 wv = W4[i4];
            Wt[(c4 + 0) * KPW + k] = f2bf(wv.x);
            Wt[(c4 + 1) * KPW + k] = f2bf(wv.y);
            Wt[(c4 + 2) * KPW + k] = f2bf(wv.z);
            Wt[(c4 + 3) * KPW + k] = f2bf(wv.w);
        }
    }
    {
        const float4* F4 = (const float4*)feat;
        #pragma unroll
        for (int it = 0; it < 16; ++it) {
            int i4 = it * 256 + tid;
            int r  = i4 >> 5;
            int c4 = (i4 & 31) * 4;
            int gr = row0 + r; if (gr >= n) gr = n - 1;
            float4 v = F4[(long)gr * 32 + (i4 & 31)];
            ushort4 u;
            u.x = f2bf(v.x); u.y = f2bf(v.y); u.z = f2bf(v.z); u.w = f2bf(v.w);
            *(ushort4*)&Fh[r * KPF + c4] = u;
        }
    }
    __syncthreads();

    const int w  = tid >> 6;
    const int l  = tid & 63;
    const int ml = l & 15;
    const int q  = l >> 4;

    float4v acc[2][4];
    #pragma unroll
    for (int rt = 0; rt < 2; ++rt)
        #pragma unroll
        for (int ct = 0; ct < 4; ++ct)
            acc[rt][ct] = (float4v){0.f, 0.f, 0.f, 0.f};

    #pragma unroll
    for (int ks = 0; ks < 4; ++ks) {
        const int ko = ks * 32 + q * 8;
        short8 a0 = *(const short8*)&Fh[(w * 32 +  0 + ml) * KPF + ko];
        short8 a1 = *(const short8*)&Fh[(w * 32 + 16 + ml) * KPF + ko];
        short8 b0 = *(const short8*)&Wt[( 0 + ml) * KPW + ko];
        short8 b1 = *(const short8*)&Wt[(16 + ml) * KPW + ko];
        short8 b2 = *(const short8*)&Wt[(32 + ml) * KPW + ko];
        short8 b3 = *(const short8*)&Wt[(48 + ml) * KPW + ko];
        acc[0][0] = __builtin_amdgcn_mfma_f32_16x16x32_bf16(a0, b0, acc[0][0], 0, 0, 0);
        acc[0][1] = __builtin_amdgcn_mfma_f32_16x16x32_bf16(a0, b1, acc[0][1], 0, 0, 0);
        acc[0][2] = __builtin_amdgcn_mfma_f32_16x16x32_bf16(a0, b2, acc[0][2], 0, 0, 0);
        acc[0][3] = __builtin_amdgcn_mfma_f32_16x16x32_bf16(a0, b3, acc[0][3], 0, 0, 0);
        acc[1][0] = __builtin_amdgcn_mfma_f32_16x16x32_bf16(a1, b0, acc[1][0], 0, 0, 0);
        acc[1][1] = __builtin_amdgcn_mfma_f32_16x16x32_bf16(a1, b1, acc[1][1], 0, 0, 0);
        acc[1][2] = __builtin_amdgcn_mfma_f32_16x16x32_bf16(a1, b2, acc[1][2], 0, 0, 0);
        acc[1][3] = __builtin_amdgcn_mfma_f32_16x16x32_bf16(a1, b3, acc[1][3], 0, 0, 0);
    }

    #pragma unroll
    for (int rt = 0; rt < 2; ++rt) {
        #pragma unroll
        for (int reg = 0; reg < 4; ++reg) {
            int row = row0 + w * 32 + rt * 16 + q * 4 + reg;
            if (row < n) {
                #pragma unroll
                for (int ct = 0; ct < 4; ++ct)
                    h[(long)row * OUT_F + ct * 16 + ml] = __float2half(acc[rt][ct][reg]);
            }
        }
    }
}

// ---- fused pass 2: work-stealing csr tasks + gather -------------------------
// Every block claims one task: [0,256) src-hist->nsrc (release-inc done_src),
// [256,512) bucket counting-sort->ebuf/off_deg (release-store flag[b]).
// Then all blocks gather (R8's proven stream-per-dst body) after spinning on
// {done_src==256, flag[own bucket]}. Progress-safe: tasks are claimed only by
// RUNNING blocks (2048 resident >= 512 tasks), so spinners always wait on work
// owned by a running block. Agent-scope release/acquire handles cross-XCD L2.
__global__ __launch_bounds__(256) void csrgather_kernel(
    const unsigned* __restrict__ bkt_d, const unsigned short* __restrict__ bkt_s,
    const int* __restrict__ gcur_d, const int* __restrict__ gcur_s,
    int2* __restrict__ off_deg, int* __restrict__ ebuf, float* __restrict__ nsrc,
    int* __restrict__ task_cur, int* __restrict__ done_src, int* __restrict__ flags,
    const __half* __restrict__ h, float* __restrict__ out, int n)
{
    __shared__ union {
        struct { int hist[512]; int curs[512]; int wsum[4]; } srt;
        int hs[512];
    } sm;
    __shared__ int s_task;

    const int tid = threadIdx.x;

    if (tid == 0) s_task = atomicAdd(task_cur, 1);
    __syncthreads();
    const int task = s_task;

    if (task < 256) {
        // ---- src-hist task: nsrc for bucket `task` (proven outdeg body) ----
        const int b = task;
        const int cnt_s = min(gcur_s[b], CAP);
        sm.hs[tid] = 0; sm.hs[tid + 256] = 0;
        __syncthreads();
        const unsigned short* sp = bkt_s + (size_t)b * CAP;
        for (int i = tid; i < cnt_s; i += 256)
            atomicAdd(&sm.hs[sp[i]], 1);
        __syncthreads();
        int node = b * 512 + tid;
        if (node < n) nsrc[node] = rsqrtf(fmaxf((float)sm.hs[tid], 1.0f));
        node += 256;
        if (node < n) nsrc[node] = rsqrtf(fmaxf((float)sm.hs[tid + 256], 1.0f));
        __syncthreads();
        if (tid == 0)
            __hip_atomic_fetch_add(done_src, 1, __ATOMIC_RELEASE,
                                   __HIP_MEMORY_SCOPE_AGENT);
    } else if (task < 512) {
        // ---- sort task: counting sort of bucket task-256 (proven csr body) --
        const int b = task - 256;
        const int cnt = min(gcur_d[b], CAP);
        sm.srt.hist[tid] = 0; sm.srt.hist[tid + 256] = 0;
        __syncthreads();
        const unsigned* bp = bkt_d + (size_t)b * CAP;
        for (int i = tid; i < cnt; i += 256)
            atomicAdd(&sm.srt.hist[bp[i] >> 17], 1);
        __syncthreads();

        int a0 = sm.srt.hist[2 * tid], a1 = sm.srt.hist[2 * tid + 1];
        int psum = a0 + a1;
        const int lane = tid & 63, w = tid >> 6;
        int x = psum;
        #pragma unroll
        for (int off = 1; off < 64; off <<= 1) {
            int y = __shfl_up(x, off);
            if (lane >= off) x += y;
        }
        if (lane == 63) sm.srt.wsum[w] = x;
        __syncthreads();
        int wbase = 0;
        for (int i = 0; i < w; ++i) wbase += sm.srt.wsum[i];
        int excl = x + wbase - psum;
        sm.srt.curs[2 * tid]     = excl;
        sm.srt.curs[2 * tid + 1] = excl + a0;
        off_deg[b * 512 + 2 * tid]     = make_int2(b * CAP + excl,      a0);
        off_deg[b * 512 + 2 * tid + 1] = make_int2(b * CAP + excl + a0, a1);
        __syncthreads();

        for (int i = tid; i < cnt; i += 256) {
            unsigned e = bp[i];
            int p = atomicAdd(&sm.srt.curs[e >> 17], 1);
            if (p < CAP) ebuf[b * CAP + p] = (int)(e & 0x1FFFFu);
        }
        __syncthreads();
        if (tid == 0)
            __hip_atomic_store(&flags[b], 1, __ATOMIC_RELEASE,
                               __HIP_MEMORY_SCOPE_AGENT);
    }

    // ---- gather phase (R8's proven stream-per-dst body, 32 dsts/block) ------
    const int bkt = blockIdx.x >> 4;       // 32 dsts/block, 512 dsts/bucket
    if (tid == 0) {
        while (__hip_atomic_load(done_src, __ATOMIC_RELAXED,
                                 __HIP_MEMORY_SCOPE_AGENT) < 256 ||
               __hip_atomic_load(&flags[bkt], __ATOMIC_RELAXED,
                                 __HIP_MEMORY_SCOPE_AGENT) == 0)
            __builtin_amdgcn_s_sleep(2);
    }
    __syncthreads();
    (void)__hip_atomic_load(&flags[bkt], __ATOMIC_ACQUIRE,
                            __HIP_MEMORY_SCOPE_AGENT);   // inv stale caches

    const int lane = threadIdx.x & 63;
    const int wv   = threadIdx.x >> 6;     // wave 0..3
    const int o    = lane >> 3;            // stream 0..7 -> dst offset in wave
    const int t    = lane & 7;             // col group: cols 8t..8t+7
    const int d    = blockIdx.x * 32 + wv * 8 + o;
    if (d >= n) return;

    int2 od = off_deg[d];
    const int beg = od.x, m = od.y, end = beg + m;

    float a0 = 0.f, a1 = 0.f, a2 = 0.f, a3 = 0.f;
    float a4 = 0.f, a5 = 0.f, a6 = 0.f, a7 = 0.f;

    int j = beg;
    for (; j + 1 < end; j += 2) {          // two independent load chains
        int sA = ebuf[j];
        int sB = ebuf[j + 1];
        float nsA = nsrc[sA];
        float nsB = nsrc[sB];
        union { uint4 u; __half2 h2[4]; } PA, PB;
        PA.u = *(const uint4*)&h[(long)sA * OUT_F + 8 * t];
        PB.u = *(const uint4*)&h[(long)sB * OUT_F + 8 * t];
        float2 fA0 = __half22float2(PA.h2[0]);
        float2 fA1 = __half22float2(PA.h2[1]);
        float2 fA2 = __half22float2(PA.h2[2]);
        float2 fA3 = __half22float2(PA.h2[3]);
        a0 = fmaf(fA0.x, nsA, a0); a1 = fmaf(fA0.y, nsA, a1);
        a2 = fmaf(fA1.x, nsA, a2); a3 = fmaf(fA1.y, nsA, a3);
        a4 = fmaf(fA2.x, nsA, a4); a5 = fmaf(fA2.y, nsA, a5);
        a6 = fmaf(fA3.x, nsA, a6); a7 = fmaf(fA3.y, nsA, a7);
        float2 fB0 = __half22float2(PB.h2[0]);
        float2 fB1 = __half22float2(PB.h2[1]);
        float2 fB2 = __half22float2(PB.h2[2]);
        float2 fB3 = __half22float2(PB.h2[3]);
        a0 = fmaf(fB0.x, nsB, a0); a1 = fmaf(fB0.y, nsB, a1);
        a2 = fmaf(fB1.x, nsB, a2); a3 = fmaf(fB1.y, nsB, a3);
        a4 = fmaf(fB2.x, nsB, a4); a5 = fmaf(fB2.y, nsB, a5);
        a6 = fmaf(fB3.x, nsB, a6); a7 = fmaf(fB3.y, nsB, a7);
    }
    if (j < end) {                         // tail edge
        int s = ebuf[j];
        float ns = nsrc[s];
        union { uint4 u; __half2 h2[4]; } P;
        P.u = *(const uint4*)&h[(long)s * OUT_F + 8 * t];
        float2 f0 = __half22float2(P.h2[0]);
        float2 f1 = __half22float2(P.h2[1]);
        float2 f2 = __half22float2(P.h2[2]);
        float2 f3 = __half22float2(P.h2[3]);
        a0 = fmaf(f0.x, ns, a0); a1 = fmaf(f0.y, ns, a1);
        a2 = fmaf(f1.x, ns, a2); a3 = fmaf(f1.y, ns, a3);
        a4 = fmaf(f2.x, ns, a4); a5 = fmaf(f2.y, ns, a5);
        a6 = fmaf(f3.x, ns, a6); a7 = fmaf(f3.y, ns, a7);
    }

    float nd = rsqrtf(fmaxf((float)m, 1.0f));
    float4 v0 = make_float4(a0 * nd, a1 * nd, a2 * nd, a3 * nd);
    float4 v1 = make_float4(a4 * nd, a5 * nd, a6 * nd, a7 * nd);
    float* op = &out[(long)d * OUT_F + 8 * t];
    *(float4*)op       = v0;    // wave writes 8 consecutive rows = 2 KB contiguous
    *(float4*)(op + 4) = v1;
}

extern "C" void kernel_launch(void* const* d_in, const int* in_sizes, int n_in,
                              void* d_out, int out_size, void* d_ws, size_t ws_size,
                              hipStream_t stream) {
    const float* feat = (const float*)d_in[0];
    const float* W    = (const float*)d_in[1];
    const int*   src  = (const int*)d_in[2];
    const int*   dst  = (const int*)d_in[3];
    float* out = (float*)d_out;

    const int n = in_sizes[0] / IN_F;     // 100000
    const int E = in_sizes[2];            // 600000

    // ---- workspace layout (~24 MB; ws is ~268 MB) ----
    char* wsb = (char*)d_ws;
    int* gcur_d   = (int*)wsb;                            // NB
    int* gcur_s   = gcur_d + NB;                          // NB
    int* task_cur = gcur_s + NB;                          // 1
    int* done_src = task_cur + 1;                         // 1
    int* flags    = done_src + 1;                         // NB
    float* nsrc   = (float*)(flags + NB);                 // n
    size_t pos = (((size_t)(3 * NB + 2 + n)) * 4 + 15) & ~(size_t)15;
    int2* off_deg = (int2*)(wsb + pos);                   // NB*512 int2 (1 MB)
    pos = (pos + (size_t)NB * 512 * 8 + 15) & ~(size_t)15;
    int* ebuf = (int*)(wsb + pos);                        // NB*CAP (3.9 MB)
    pos = (pos + (size_t)NB * CAP * 4 + 15) & ~(size_t)15;
    unsigned* bkt_d = (unsigned*)(wsb + pos);             // NB*CAP u32 (3.9 MB)
    pos = (pos + (size_t)NB * CAP * 4 + 15) & ~(size_t)15;
    unsigned short* bkt_s = (unsigned short*)(wsb + pos); // NB*CAP u16 (2.0 MB)
    pos = (pos + (size_t)NB * CAP * 2 + 15) & ~(size_t)15;
    __half* h = (__half*)(wsb + pos);                     // n*64 fp16 (12.8 MB)

    hipMemsetAsync(gcur_d, 0, (3 * NB + 2) * sizeof(int), stream);

    const int nbin  = (E + CHUNK - 1) / CHUNK;            // 293
    const int ngemm = (n + 127) / 128;                    // 782

    bin_gemm_kernel<<<nbin + ngemm, 256, 0, stream>>>(src, dst, gcur_d, gcur_s,
                                                      bkt_d, bkt_s, E, nbin,
                                                      feat, W, h, n);
    csrgather_kernel<<<(n + 31) / 32, 256, 0, stream>>>(bkt_d, bkt_s, gcur_d, gcur_s,
                                                        off_deg, ebuf, nsrc,
                                                        task_cur, done_src, flags,
                                                        h, out, n);
}

// Round 12
// 132.530 us; speedup vs baseline: 2.5545x; 2.5545x over previous
//
#include <hip/hip_runtime.h>
#include <hip/hip_fp16.h>

#define IN_F 128
#define OUT_F 64
#define NB    256     // node-range buckets, 512 nodes each
#define BSH   9
#define CAP   3840    // per-bucket capacity (lambda=2344, +31 sigma, proven R4-R7)
#define CHUNK 2048    // edges per bin block
#define KPF  136      // Fh k-pitch (bf16 elems)
#define KPW  144      // Wt k-pitch (bf16 elems)

using short8  = __attribute__((ext_vector_type(8))) short;
using float4v = __attribute__((ext_vector_type(4))) float;

static __device__ inline unsigned short f2bf(float x) {
    union { float f; unsigned u; } v; v.f = x;
    unsigned r = (v.u + 0x7fffu + ((v.u >> 16) & 1u)) >> 16;  // RN-even
    return (unsigned short)r;
}

// ---- fused pass 1: edge binning INTERLEAVED with GEMM (R8's proven kernel) --
__global__ __launch_bounds__(256) void bin_gemm_kernel(
    const int* __restrict__ src, const int* __restrict__ dst,
    int* __restrict__ gcur_d, int* __restrict__ gcur_s,
    unsigned* __restrict__ bkt_d, unsigned short* __restrict__ bkt_s,
    int E, int nbin,
    const float* __restrict__ feat, const float* __restrict__ W,
    __half* __restrict__ h, int n)
{
    __shared__ union {
        struct { int hd[NB]; int hs[NB]; int based[NB]; int bases[NB]; } bin;
        struct { unsigned short Fh[128 * KPF]; unsigned short Wt[64 * KPW]; } gm;
    } smem;

    const int tid = threadIdx.x;
    const int b   = blockIdx.x;
    const int G   = gridDim.x;
    const int f   = (int)(((long)b       * nbin) / G);   // bin blocks before b
    const int c   = (int)(((long)(b + 1) * nbin) / G);
    const bool is_bin = (c > f);

    if (is_bin) {
        // ---------------- bin path (proven structure; bin block index = f) ---
        const int e0 = f * CHUNK;

        smem.bin.hd[tid] = 0; smem.bin.hs[tid] = 0;
        __syncthreads();

        int sv[8], dv[8];
        #pragma unroll
        for (int j = 0; j < 8; ++j) {
            int i = e0 + j * 256 + tid;          // coalesced
            if (i < E) { sv[j] = src[i]; dv[j] = dst[i]; }
            else       { sv[j] = -1;     dv[j] = -1; }
        }
        #pragma unroll
        for (int j = 0; j < 8; ++j) {
            if (dv[j] >= 0) {
                atomicAdd(&smem.bin.hd[dv[j] >> BSH], 1);
                atomicAdd(&smem.bin.hs[sv[j] >> BSH], 1);
            }
        }
        __syncthreads();

        int cd = smem.bin.hd[tid], cs = smem.bin.hs[tid];
        smem.bin.based[tid] = cd ? atomicAdd(&gcur_d[tid], cd) : 0;
        smem.bin.bases[tid] = cs ? atomicAdd(&gcur_s[tid], cs) : 0;
        smem.bin.hd[tid] = 0; smem.bin.hs[tid] = 0;   // reuse as local cursors
        __syncthreads();

        #pragma unroll
        for (int j = 0; j < 8; ++j) {
            if (dv[j] >= 0) {
                int bd = dv[j] >> BSH;
                int pd = atomicAdd(&smem.bin.hd[bd], 1) + smem.bin.based[bd];
                if (pd < CAP)
                    bkt_d[(size_t)bd * CAP + pd] =
                        (unsigned)sv[j] | ((unsigned)(dv[j] & 511) << 17);  // src < 2^17
                int bs = sv[j] >> BSH;
                int ps = atomicAdd(&smem.bin.hs[bs], 1) + smem.bin.bases[bs];
                if (ps < CAP) bkt_s[(size_t)bs * CAP + ps] = (unsigned short)(sv[j] & 511);
            }
        }
        return;
    }

    // ---------------- gemm path: h = feat @ W (raw fp16; ns applied in gather)
    unsigned short* Fh = smem.gm.Fh;
    unsigned short* Wt = smem.gm.Wt;
    const int row0 = (b - f) * 128;           // gemm block index = b - f

    {
        const float4* W4 = (const float4*)W;
        #pragma unroll
        for (int it = 0; it < 8; ++it) {
            int i4 = it * 256 + tid;
            int k  = i4 >> 4;
            int c4 = (i4 & 15) * 4;
            float4 wv = W4[i4];
            Wt[(c4 + 0) * KPW + k] = f2bf(wv.x);
            Wt[(c4 + 1) * KPW + k] = f2bf(wv.y);
            Wt[(c4 + 2) * KPW + k] = f2bf(wv.z);
            Wt[(c4 + 3) * KPW + k] = f2bf(wv.w);
        }
    }
    {
        const float4* F4 = (const float4*)feat;
        #pragma unroll
        for (int it = 0; it < 16; ++it) {
            int i4 = it * 256 + tid;
            int r  = i4 >> 5;
            int c4 = (i4 & 31) * 4;
            int gr = row0 + r; if (gr >= n) gr = n - 1;
            float4 v = F4[(long)gr * 32 + (i4 & 31)];
            ushort4 u;
            u.x = f2bf(v.x); u.y = f2bf(v.y); u.z = f2bf(v.z); u.w = f2bf(v.w);
            *(ushort4*)&Fh[r * KPF + c4] = u;
        }
    }
    __syncthreads();

    const int w  = tid >> 6;
    const int l  = tid & 63;
    const int ml = l & 15;
    const int q  = l >> 4;

    float4v acc[2][4];
    #pragma unroll
    for (int rt = 0; rt < 2; ++rt)
        #pragma unroll
        for (int ct = 0; ct < 4; ++ct)
            acc[rt][ct] = (float4v){0.f, 0.f, 0.f, 0.f};

    #pragma unroll
    for (int ks = 0; ks < 4; ++ks) {
        const int ko = ks * 32 + q * 8;
        short8 a0 = *(const short8*)&Fh[(w * 32 +  0 + ml) * KPF + ko];
        short8 a1 = *(const short8*)&Fh[(w * 32 + 16 + ml) * KPF + ko];
        short8 b0 = *(const short8*)&Wt[( 0 + ml) * KPW + ko];
        short8 b1 = *(const short8*)&Wt[(16 + ml) * KPW + ko];
        short8 b2 = *(const short8*)&Wt[(32 + ml) * KPW + ko];
        short8 b3 = *(const short8*)&Wt[(48 + ml) * KPW + ko];
        acc[0][0] = __builtin_amdgcn_mfma_f32_16x16x32_bf16(a0, b0, acc[0][0], 0, 0, 0);
        acc[0][1] = __builtin_amdgcn_mfma_f32_16x16x32_bf16(a0, b1, acc[0][1], 0, 0, 0);
        acc[0][2] = __builtin_amdgcn_mfma_f32_16x16x32_bf16(a0, b2, acc[0][2], 0, 0, 0);
        acc[0][3] = __builtin_amdgcn_mfma_f32_16x16x32_bf16(a0, b3, acc[0][3], 0, 0, 0);
        acc[1][0] = __builtin_amdgcn_mfma_f32_16x16x32_bf16(a1, b0, acc[1][0], 0, 0, 0);
        acc[1][1] = __builtin_amdgcn_mfma_f32_16x16x32_bf16(a1, b1, acc[1][1], 0, 0, 0);
        acc[1][2] = __builtin_amdgcn_mfma_f32_16x16x32_bf16(a1, b2, acc[1][2], 0, 0, 0);
        acc[1][3] = __builtin_amdgcn_mfma_f32_16x16x32_bf16(a1, b3, acc[1][3], 0, 0, 0);
    }

    #pragma unroll
    for (int rt = 0; rt < 2; ++rt) {
        #pragma unroll
        for (int reg = 0; reg < 4; ++reg) {
            int row = row0 + w * 32 + rt * 16 + q * 4 + reg;
            if (row < n) {
                #pragma unroll
                for (int ct = 0; ct < 4; ++ct)
                    h[(long)row * OUT_F + ct * 16 + ml] = __float2half(acc[rt][ct][reg]);
            }
        }
    }
}

// ---- pass 2: per-bucket counting sort + nsrc + off_deg, 1024 threads --------
// Same proven csr body, but 16 waves/CU (was 4): hist/scatter loops stride
// 1024, so LDS-atomic latency is hidden by 4x the TLP. Scan in threads 0-511.
__global__ __launch_bounds__(1024) void csr_kernel(
    const unsigned* __restrict__ bkt_d, const unsigned short* __restrict__ bkt_s,
    const int* __restrict__ gcur_d, const int* __restrict__ gcur_s,
    int2* __restrict__ off_deg, int* __restrict__ ebuf, float* __restrict__ nsrc, int n)
{
    __shared__ int hist[512], curs[512], hist_s[512];
    __shared__ int wsum[8];
    const int b = blockIdx.x, tid = threadIdx.x;
    const int cnt   = min(gcur_d[b], CAP);
    const int cnt_s = min(gcur_s[b], CAP);

    if (tid < 512) { hist[tid] = 0; hist_s[tid] = 0; }
    __syncthreads();

    const unsigned* bp = bkt_d + (size_t)b * CAP;
    for (int i = tid; i < cnt; i += 1024)
        atomicAdd(&hist[bp[i] >> 17], 1);
    const unsigned short* sp = bkt_s + (size_t)b * CAP;
    for (int i = tid; i < cnt_s; i += 1024)
        atomicAdd(&hist_s[sp[i]], 1);
    __syncthreads();

    // exclusive scan of hist[512] in threads 0..511 (waves 0..7)
    const int lane = tid & 63, w = tid >> 6;
    int deg = 0, x = 0;
    if (tid < 512) {
        deg = hist[tid];
        x = deg;
        #pragma unroll
        for (int off = 1; off < 64; off <<= 1) {
            int y = __shfl_up(x, off);
            if (lane >= off) x += y;
        }
        if (lane == 63) wsum[w] = x;
    }
    __syncthreads();
    if (tid < 512) {
        int wbase = 0;
        for (int i = 0; i < w; ++i) wbase += wsum[i];
        int excl = x + wbase - deg;
        curs[tid] = excl;
        off_deg[b * 512 + tid] = make_int2(b * CAP + excl, deg);
        // nsrc writeout (src-side histogram -> rsqrt)
        int node = b * 512 + tid;
        if (node < n) nsrc[node] = rsqrtf(fmaxf((float)hist_s[tid], 1.0f));
    }
    __syncthreads();

    // sorted scatter straight to global; bucket window re-read is L1/L2-hot
    for (int i = tid; i < cnt; i += 1024) {
        unsigned e = bp[i];
        int p = atomicAdd(&curs[e >> 17], 1);
        if (p < CAP) ebuf[b * CAP + p] = (int)(e & 0x1FFFFu);
    }
}

// ---- pull aggregation, stream-per-dst (R8's proven kernel) ------------------
// out stores are nontemporal (via clang ext_vector float4v — HIP's float4 is a
// struct and rejected by the builtin): 25.6 MB written once, never re-read ->
// keep L2 free for the 6x-reused h table.
__global__ __launch_bounds__(256) void gather_kernel(
    const int* __restrict__ ebuf, const int2* __restrict__ off_deg,
    const float* __restrict__ nsrc,
    const __half* __restrict__ h, float* __restrict__ out, int n)
{
    const int lane = threadIdx.x & 63;
    const int wv   = threadIdx.x >> 6;     // wave 0..3
    const int o    = lane >> 3;            // stream 0..7 -> dst offset in wave
    const int t    = lane & 7;             // col group: cols 8t..8t+7
    const int d    = blockIdx.x * 32 + wv * 8 + o;
    if (d >= n) return;

    int2 od = off_deg[d];
    const int beg = od.x, m = od.y, end = beg + m;

    float a0 = 0.f, a1 = 0.f, a2 = 0.f, a3 = 0.f;
    float a4 = 0.f, a5 = 0.f, a6 = 0.f, a7 = 0.f;

    int j = beg;
    for (; j + 1 < end; j += 2) {          // two independent load chains
        int sA = ebuf[j];
        int sB = ebuf[j + 1];
        float nsA = nsrc[sA];
        float nsB = nsrc[sB];
        union { uint4 u; __half2 h2[4]; } PA, PB;
        PA.u = *(const uint4*)&h[(long)sA * OUT_F + 8 * t];
        PB.u = *(const uint4*)&h[(long)sB * OUT_F + 8 * t];
        float2 fA0 = __half22float2(PA.h2[0]);
        float2 fA1 = __half22float2(PA.h2[1]);
        float2 fA2 = __half22float2(PA.h2[2]);
        float2 fA3 = __half22float2(PA.h2[3]);
        a0 = fmaf(fA0.x, nsA, a0); a1 = fmaf(fA0.y, nsA, a1);
        a2 = fmaf(fA1.x, nsA, a2); a3 = fmaf(fA1.y, nsA, a3);
        a4 = fmaf(fA2.x, nsA, a4); a5 = fmaf(fA2.y, nsA, a5);
        a6 = fmaf(fA3.x, nsA, a6); a7 = fmaf(fA3.y, nsA, a7);
        float2 fB0 = __half22float2(PB.h2[0]);
        float2 fB1 = __half22float2(PB.h2[1]);
        float2 fB2 = __half22float2(PB.h2[2]);
        float2 fB3 = __half22float2(PB.h2[3]);
        a0 = fmaf(fB0.x, nsB, a0); a1 = fmaf(fB0.y, nsB, a1);
        a2 = fmaf(fB1.x, nsB, a2); a3 = fmaf(fB1.y, nsB, a3);
        a4 = fmaf(fB2.x, nsB, a4); a5 = fmaf(fB2.y, nsB, a5);
        a6 = fmaf(fB3.x, nsB, a6); a7 = fmaf(fB3.y, nsB, a7);
    }
    if (j < end) {                         // tail edge
        int s = ebuf[j];
        float ns = nsrc[s];
        union { uint4 u; __half2 h2[4]; } P;
        P.u = *(const uint4*)&h[(long)s * OUT_F + 8 * t];
        float2 f0 = __half22float2(P.h2[0]);
        float2 f1 = __half22float2(P.h2[1]);
        float2 f2 = __half22float2(P.h2[2]);
        float2 f3 = __half22float2(P.h2[3]);
        a0 = fmaf(f0.x, ns, a0); a1 = fmaf(f0.y, ns, a1);
        a2 = fmaf(f1.x, ns, a2); a3 = fmaf(f1.y, ns, a3);
        a4 = fmaf(f2.x, ns, a4); a5 = fmaf(f2.y, ns, a5);
        a6 = fmaf(f3.x, ns, a6); a7 = fmaf(f3.y, ns, a7);
    }

    float nd = rsqrtf(fmaxf((float)m, 1.0f));
    float4v v0 = {a0 * nd, a1 * nd, a2 * nd, a3 * nd};
    float4v v1 = {a4 * nd, a5 * nd, a6 * nd, a7 * nd};
    float* op = &out[(long)d * OUT_F + 8 * t];
    __builtin_nontemporal_store(v0, (float4v*)op);      // 2 KB contiguous/wave
    __builtin_nontemporal_store(v1, (float4v*)(op + 4));
}

extern "C" void kernel_launch(void* const* d_in, const int* in_sizes, int n_in,
                              void* d_out, int out_size, void* d_ws, size_t ws_size,
                              hipStream_t stream) {
    const float* feat = (const float*)d_in[0];
    const float* W    = (const float*)d_in[1];
    const int*   src  = (const int*)d_in[2];
    const int*   dst  = (const int*)d_in[3];
    float* out = (float*)d_out;

    const int n = in_sizes[0] / IN_F;     // 100000
    const int E = in_sizes[2];            // 600000

    // ---- workspace layout (~24 MB; ws is ~268 MB) ----
    char* wsb = (char*)d_ws;
    int* gcur_d = (int*)wsb;                              // NB
    int* gcur_s = gcur_d + NB;                            // NB
    float* nsrc = (float*)(gcur_s + NB);                  // n
    size_t pos = (((size_t)(2 * NB + n)) * 4 + 15) & ~(size_t)15;
    int2* off_deg = (int2*)(wsb + pos);                   // NB*512 int2 (1 MB)
    pos = (pos + (size_t)NB * 512 * 8 + 15) & ~(size_t)15;
    int* ebuf = (int*)(wsb + pos);                        // NB*CAP (3.9 MB)
    pos = (pos + (size_t)NB * CAP * 4 + 15) & ~(size_t)15;
    unsigned* bkt_d = (unsigned*)(wsb + pos);             // NB*CAP u32 (3.9 MB)
    pos = (pos + (size_t)NB * CAP * 4 + 15) & ~(size_t)15;
    unsigned short* bkt_s = (unsigned short*)(wsb + pos); // NB*CAP u16 (2.0 MB)
    pos = (pos + (size_t)NB * CAP * 2 + 15) & ~(size_t)15;
    __half* h = (__half*)(wsb + pos);                     // n*64 fp16 (12.8 MB)

    hipMemsetAsync(gcur_d, 0, 2 * NB * sizeof(int), stream);

    const int nbin  = (E + CHUNK - 1) / CHUNK;            // 293
    const int ngemm = (n + 127) / 128;                    // 782

    bin_gemm_kernel<<<nbin + ngemm, 256, 0, stream>>>(src, dst, gcur_d, gcur_s,
                                                      bkt_d, bkt_s, E, nbin,
                                                      feat, W, h, n);
    csr_kernel<<<NB, 1024, 0, stream>>>(bkt_d, bkt_s, gcur_d, gcur_s,
                                        off_deg, ebuf, nsrc, n);
    gather_kernel<<<(n + 31) / 32, 256, 0, stream>>>(ebuf, off_deg, nsrc, h, out, n);
}